// Round 1
// baseline (36481.305 us; speedup 1.0000x reference)
//
#include <hip/hip_runtime.h>
#include <hip/hip_bf16.h>
#include <math.h>

// ---------------------------------------------------------------------------
// Problem constants
// ---------------------------------------------------------------------------
#define BATCH 4
#define S_V 768
#define S_E 64
#define SEQ 832          // S_V + S_E
#define W_V 2048
#define W_E 1024
#define NH 8
#define DH 256
#define MLP_V 16384
#define MLP_E 4096
#define EPS 1e-6f
#define ATT_SCALE 0.0625f   // 256^-0.5

// ---------------------------------------------------------------------------
// Generic tiled f32 GEMM: C = op(A @ B)
//   Row mapping (handles [B, S, ...] packing):
//     A row m lives at A + (m/rpb)*a_bs + (m%rpb)*K
//     C row m lives at C + (m/rpb)*c_bs + (m%rpb)*N
//     res row m at      res + (m/rpb)*r_bs + (m%rpb)*N
//   flags: 1 = add res, 2 = multiply by gate[b*3072 + gate_off + n],
//          4 = accumulate into existing C
//   Requires M%128==0, N%128==0, K%16==0 (all shapes here satisfy this).
// ---------------------------------------------------------------------------
#define BM 128
#define BN 128
#define BK 16

__global__ __launch_bounds__(256) void gemm_k(
    const float* __restrict__ A, const float* __restrict__ Bm,
    float* __restrict__ C,
    const float* __restrict__ res, const float* __restrict__ gate,
    int gate_off, int M, int N, int K, int rpb,
    long long a_bs, long long c_bs, long long r_bs, int flags)
{
    __shared__ float As[BK][BM + 4];
    __shared__ float Bs[BK][BN + 4];

    const int tid = threadIdx.x;
    const int bm = blockIdx.y * BM;
    const int bn = blockIdx.x * BN;
    const int tx = tid & 15;
    const int ty = tid >> 4;

    float acc[8][8];
#pragma unroll
    for (int i = 0; i < 8; i++)
#pragma unroll
        for (int j = 0; j < 8; j++) acc[i][j] = 0.f;

    for (int kt = 0; kt < K; kt += BK) {
        // A tile: 128 rows x 16 k  (512 float4 loads, 2 per thread)
#pragma unroll
        for (int l = 0; l < 2; l++) {
            int idx = tid + l * 256;          // 0..511
            int r   = idx >> 2;               // 0..127
            int c4  = (idx & 3) << 2;         // 0,4,8,12
            int m   = bm + r;
            const float* ap = A + (long long)(m / rpb) * a_bs
                                + (long long)(m % rpb) * K + kt + c4;
            float4 v4 = *(const float4*)ap;
            As[c4 + 0][r] = v4.x;
            As[c4 + 1][r] = v4.y;
            As[c4 + 2][r] = v4.z;
            As[c4 + 3][r] = v4.w;
        }
        // B tile: 16 k-rows x 128 cols (512 float4 loads, 2 per thread)
#pragma unroll
        for (int l = 0; l < 2; l++) {
            int idx = tid + l * 256;
            int kr  = idx >> 5;               // 0..15
            int c4  = (idx & 31) << 2;        // 0..124
            const float* bp = Bm + (long long)(kt + kr) * N + bn + c4;
            *(float4*)&Bs[kr][c4] = *(const float4*)bp;
        }
        __syncthreads();

#pragma unroll
        for (int kk = 0; kk < BK; kk++) {
            float4 a0 = *(const float4*)&As[kk][ty * 4];
            float4 a1 = *(const float4*)&As[kk][64 + ty * 4];
            float4 b0 = *(const float4*)&Bs[kk][tx * 4];
            float4 b1 = *(const float4*)&Bs[kk][64 + tx * 4];
            float av[8] = {a0.x, a0.y, a0.z, a0.w, a1.x, a1.y, a1.z, a1.w};
            float bv[8] = {b0.x, b0.y, b0.z, b0.w, b1.x, b1.y, b1.z, b1.w};
#pragma unroll
            for (int i = 0; i < 8; i++)
#pragma unroll
                for (int j = 0; j < 8; j++) acc[i][j] += av[i] * bv[j];
        }
        __syncthreads();
    }

    // epilogue
#pragma unroll
    for (int i = 0; i < 8; i++) {
        int m = bm + ((i < 4) ? (ty * 4 + i) : (64 + ty * 4 + (i - 4)));
        long long b = m / rpb;
        long long s = m % rpb;
        float* cp = C + b * c_bs + s * (long long)N;
        const float* rp = (flags & 1) ? (res + b * r_bs + s * (long long)N) : nullptr;
        const float* gp = (flags & 2) ? (gate + b * 3072 + gate_off) : nullptr;
#pragma unroll
        for (int j = 0; j < 8; j++) {
            int n = bn + ((j < 4) ? (tx * 4 + j) : (64 + tx * 4 + (j - 4)));
            float v = acc[i][j];
            if (flags & 2) v *= gp[n];
            if (flags & 4) v += cp[n];
            if (flags & 1) v += rp[n];
            cp[n] = v;
        }
    }
}

// ---------------------------------------------------------------------------
// RMSNorm * (1 + w) : one block per row
// ---------------------------------------------------------------------------
__global__ __launch_bounds__(256) void rms_scale_k(
    const float* __restrict__ x, const float* __restrict__ w,
    float* __restrict__ out, int C)
{
    const int row = blockIdx.x;
    const int t = threadIdx.x;
    const float* xp = x + (long long)row * C;
    float* op = out + (long long)row * C;

    float ss = 0.f;
    for (int i = t; i < C; i += 256) { float v = xp[i]; ss += v * v; }
    __shared__ float sred[256];
    sred[t] = ss;
    __syncthreads();
    for (int off = 128; off > 0; off >>= 1) {
        if (t < off) sred[t] += sred[t + off];
        __syncthreads();
    }
    float scale = rsqrtf(sred[0] / (float)C + EPS);
    for (int i = t; i < C; i += 256) op[i] = xp[i] * scale * (1.f + w[i]);
}

// ---------------------------------------------------------------------------
// adaLN-modulated RMSNorm: out = rms(x)*(1+mod[b, i]) + mod[b, C+i]
// mod layout [B, 3072]
// ---------------------------------------------------------------------------
__global__ __launch_bounds__(256) void rms_mod_k(
    const float* __restrict__ x, const float* __restrict__ mod,
    float* __restrict__ out, int C, int rows_per_b)
{
    const int row = blockIdx.x;
    const int t = threadIdx.x;
    const int b = row / rows_per_b;
    const float* xp = x + (long long)row * C;
    const float* mp = mod + (long long)b * 3072;
    float* op = out + (long long)row * C;

    float ss = 0.f;
    for (int i = t; i < C; i += 256) { float v = xp[i]; ss += v * v; }
    __shared__ float sred[256];
    sred[t] = ss;
    __syncthreads();
    for (int off = 128; off > 0; off >>= 1) {
        if (t < off) sred[t] += sred[t + off];
        __syncthreads();
    }
    float scale = rsqrtf(sred[0] / (float)C + EPS);
    for (int i = t; i < C; i += 256)
        op[i] = xp[i] * scale * (1.f + mp[i]) + mp[C + i];
}

// ---------------------------------------------------------------------------
// Modulation: mod[b, n] = sum_k cond[b,k] * dw[k,n] + db[n]   (n < 3072, k < 1024)
// ---------------------------------------------------------------------------
__global__ __launch_bounds__(256) void modln_k(
    const float* __restrict__ cond, const float* __restrict__ dw,
    const float* __restrict__ db, float* __restrict__ out)
{
    const int b = blockIdx.y;
    const int n = blockIdx.x * 256 + threadIdx.x;   // 0..3071
    __shared__ float cs[1024];
    for (int i = threadIdx.x; i < 1024; i += 256) cs[i] = cond[b * 1024 + i];
    __syncthreads();
    float acc = db[n];
    for (int k = 0; k < 1024; k++) acc += cs[k] * dw[(long long)k * 3072 + n];
    out[b * 3072 + n] = acc;
}

// ---------------------------------------------------------------------------
// RoPE in place on x[B, SEQ, heads, DH]; pos from position_ids[B, SEQ]
// block 128 threads = pair (d, d+128); grid (B*SEQ, heads)
// ---------------------------------------------------------------------------
__global__ __launch_bounds__(128) void rope_k(
    float* __restrict__ x, const int* __restrict__ pos_ids, int heads)
{
    const int bs = blockIdx.x;            // b*SEQ + s
    const int h = blockIdx.y;
    const int d = threadIdx.x;            // 0..127
    const float p = (float)pos_ids[bs];
    const float inv = powf(10000.f, -(float)d / 128.f);
    const float fr = p * inv;
    const float c = cosf(fr), sn = sinf(fr);
    float* xp = x + ((long long)bs * heads + h) * DH;
    float x1 = xp[d];
    float x2 = xp[d + 128];
    xp[d]       = x1 * c - x2 * sn;
    xp[d + 128] = x2 * c + x1 * sn;
}

// ---------------------------------------------------------------------------
// Attention: q[B,SEQ,NH,DH] (in/out in place), k/v[B,SEQ,DH] (HKV=1 broadcast)
// 8 q-rows per block; mask: kk<768 always allowed; expert rows also kk<=r.
// ---------------------------------------------------------------------------
__global__ __launch_bounds__(256) void attn_k(
    float* __restrict__ q, const float* __restrict__ k, const float* __restrict__ v)
{
    const int r0 = blockIdx.x * 8;
    const int h = blockIdx.y;
    const int b = blockIdx.z;
    const int t = threadIdx.x;

    __shared__ float qs[8][DH];
    __shared__ float ps[8][SEQ];
    __shared__ float sred[256];
    __shared__ float srinv[8];

    // stage q rows for this head
#pragma unroll
    for (int r8 = 0; r8 < 8; r8++)
        qs[r8][t] = q[((long long)(b * SEQ + r0 + r8) * NH + h) * DH + t];
    __syncthreads();

    // logits
    for (int p = t; p < 8 * SEQ; p += 256) {
        int r8 = p / SEQ;
        int kk = p % SEQ;
        int r = r0 + r8;
        bool ok = (kk < S_V) || (r >= S_V && kk <= r);
        if (ok) {
            const float4* kp = (const float4*)(k + (long long)(b * SEQ + kk) * DH);
            const float4* qp = (const float4*)qs[r8];
            float acc = 0.f;
#pragma unroll 4
            for (int d4 = 0; d4 < DH / 4; d4++) {
                float4 kv = kp[d4];
                float4 qv = qp[d4];
                acc += qv.x * kv.x + qv.y * kv.y + qv.z * kv.z + qv.w * kv.w;
            }
            ps[r8][kk] = acc * ATT_SCALE;
        } else {
            ps[r8][kk] = -1e30f;
        }
    }
    __syncthreads();

    // softmax per row
    for (int r8 = 0; r8 < 8; r8++) {
        float lm = -1e30f;
        for (int kk = t; kk < SEQ; kk += 256) lm = fmaxf(lm, ps[r8][kk]);
        sred[t] = lm;
        __syncthreads();
        for (int off = 128; off > 0; off >>= 1) {
            if (t < off) sred[t] = fmaxf(sred[t], sred[t + off]);
            __syncthreads();
        }
        float m = sred[0];
        __syncthreads();
        float lsum = 0.f;
        for (int kk = t; kk < SEQ; kk += 256) {
            float e = expf(ps[r8][kk] - m);
            ps[r8][kk] = e;
            lsum += e;
        }
        sred[t] = lsum;
        __syncthreads();
        for (int off = 128; off > 0; off >>= 1) {
            if (t < off) sred[t] += sred[t + off];
            __syncthreads();
        }
        if (t == 0) srinv[r8] = 1.f / sred[0];
        __syncthreads();
    }

    // out[d=t] = sum_kk p * v[kk, d]
    float acc[8];
#pragma unroll
    for (int r8 = 0; r8 < 8; r8++) acc[r8] = 0.f;
    for (int kk = 0; kk < SEQ; kk++) {
        float vv = v[(long long)(b * SEQ + kk) * DH + t];
#pragma unroll
        for (int r8 = 0; r8 < 8; r8++) acc[r8] += ps[r8][kk] * vv;
    }
#pragma unroll
    for (int r8 = 0; r8 < 8; r8++)
        q[((long long)(b * SEQ + r0 + r8) * NH + h) * DH + t] = acc[r8] * srinv[r8];
}

// ---------------------------------------------------------------------------
// g = gelu_tanh(g) * u, elementwise
// ---------------------------------------------------------------------------
__global__ __launch_bounds__(256) void gelu_mul_k(
    float* __restrict__ g, const float* __restrict__ u, long long n)
{
    long long i = (long long)blockIdx.x * 256 + threadIdx.x;
    long long stride = (long long)gridDim.x * 256;
    for (; i < n; i += stride) {
        float x = g[i];
        float th = tanhf(0.7978845608028654f * (x + 0.044715f * x * x * x));
        g[i] = 0.5f * x * (1.f + th) * u[i];
    }
}

// ---------------------------------------------------------------------------
// kernel_launch
// ---------------------------------------------------------------------------
extern "C" void kernel_launch(void* const* d_in, const int* in_sizes, int n_in,
                              void* d_out, int out_size, void* d_ws, size_t ws_size,
                              hipStream_t stream)
{
    const float* embeds_vlm = (const float*)d_in[0];
    const float* embeds_exp = (const float*)d_in[1];
    const float* cond       = (const float*)d_in[2];
    const float* vlm_ln1_w  = (const float*)d_in[3];
    const float* vlm_ln2_w  = (const float*)d_in[4];
    const float* vlm_q_w    = (const float*)d_in[5];
    const float* vlm_k_w    = (const float*)d_in[6];
    const float* vlm_v_w    = (const float*)d_in[7];
    const float* vlm_o_w    = (const float*)d_in[8];
    const float* vlm_gate_w = (const float*)d_in[9];
    const float* vlm_up_w   = (const float*)d_in[10];
    const float* vlm_down_w = (const float*)d_in[11];
    const float* exp_ln1_dw = (const float*)d_in[12];
    const float* exp_ln1_db = (const float*)d_in[13];
    const float* exp_ln2_dw = (const float*)d_in[14];
    const float* exp_ln2_db = (const float*)d_in[15];
    const float* exp_q_w    = (const float*)d_in[16];
    const float* exp_k_w    = (const float*)d_in[17];
    const float* exp_v_w    = (const float*)d_in[18];
    const float* exp_o_w    = (const float*)d_in[19];
    const float* exp_gate_w = (const float*)d_in[20];
    const float* exp_up_w   = (const float*)d_in[21];
    const float* exp_down_w = (const float*)d_in[22];
    const int*   position_ids = (const int*)d_in[23];
    // d_in[24] = attn_mask (re-derived analytically)

    float* OUTV = (float*)d_out;                       // [B, S_V, W_V]
    float* OUTE = OUTV + (long long)BATCH * S_V * W_V; // [B, S_E, W_E]

    // workspace layout (floats)
    float* W0   = (float*)d_ws;          // hv / nv : 3072 x 2048
    float* W1   = W0 + 6291456;          // he / ne : 256 x 1024
    float* MOD1 = W1 + 262144;           // 4 x 3072
    float* MOD2 = MOD1 + 12288;          // 4 x 3072
    float* Q    = MOD2 + 12288;          // q / attn-out : [B, SEQ, NH*DH] (6,815,744)
    float* Kb   = Q + 6815744;           // [B, SEQ, DH]
    float* Vb   = Kb + 851968;           // [B, SEQ, DH]
    float* AG   = Vb + 851968;           // act gate scratch : 384 x 16384
    float* AU   = Q;                     // act up reuses Q after attention is consumed

    // 1) hv = rms(embeds_vlm) * (1 + vlm_ln1_w)
    rms_scale_k<<<BATCH * S_V, 256, 0, stream>>>(embeds_vlm, vlm_ln1_w, W0, W_V);

    // 2) mod1 / mod2
    modln_k<<<dim3(12, BATCH), 256, 0, stream>>>(cond, exp_ln1_dw, exp_ln1_db, MOD1);
    modln_k<<<dim3(12, BATCH), 256, 0, stream>>>(cond, exp_ln2_dw, exp_ln2_db, MOD2);

    // 3) he = rms(embeds_exp)*(1+s1) + sh1
    rms_mod_k<<<BATCH * S_E, 256, 0, stream>>>(embeds_exp, MOD1, W1, W_E, S_E);

    const long long QBS = (long long)SEQ * (NH * DH);  // 832*2048 q batch stride
    const long long KBS = (long long)SEQ * DH;         // 832*256

    // 4) projections (batch-strided destinations interleave vlm rows [0,768) / exp rows [768,832))
    gemm_k<<<dim3(16, 24), 256, 0, stream>>>(W0, vlm_q_w, Q, nullptr, nullptr, 0,
        3072, 2048, 2048, S_V, (long long)S_V * W_V, QBS, 0, 0);
    gemm_k<<<dim3(2, 24), 256, 0, stream>>>(W0, vlm_k_w, Kb, nullptr, nullptr, 0,
        3072, 256, 2048, S_V, (long long)S_V * W_V, KBS, 0, 0);
    gemm_k<<<dim3(2, 24), 256, 0, stream>>>(W0, vlm_v_w, Vb, nullptr, nullptr, 0,
        3072, 256, 2048, S_V, (long long)S_V * W_V, KBS, 0, 0);

    gemm_k<<<dim3(16, 2), 256, 0, stream>>>(W1, exp_q_w, Q + (long long)S_V * 2048,
        nullptr, nullptr, 0, 256, 2048, 1024, S_E, (long long)S_E * W_E, QBS, 0, 0);
    gemm_k<<<dim3(2, 2), 256, 0, stream>>>(W1, exp_k_w, Kb + (long long)S_V * DH,
        nullptr, nullptr, 0, 256, 256, 1024, S_E, (long long)S_E * W_E, KBS, 0, 0);
    gemm_k<<<dim3(2, 2), 256, 0, stream>>>(W1, exp_v_w, Vb + (long long)S_V * DH,
        nullptr, nullptr, 0, 256, 256, 1024, S_E, (long long)S_E * W_E, KBS, 0, 0);

    // 5) RoPE on q (8 heads) and k (1 head)
    rope_k<<<dim3(BATCH * SEQ, NH), 128, 0, stream>>>(Q, position_ids, NH);
    rope_k<<<dim3(BATCH * SEQ, 1), 128, 0, stream>>>(Kb, position_ids, 1);

    // 6) attention (in-place on Q)
    attn_k<<<dim3(SEQ / 8, NH, BATCH), 256, 0, stream>>>(Q, Kb, Vb);

    // 7) o-projections with residual
    gemm_k<<<dim3(16, 24), 256, 0, stream>>>(Q, vlm_o_w, OUTV, embeds_vlm, nullptr, 0,
        3072, 2048, 2048, S_V, QBS, (long long)S_V * W_V, (long long)S_V * W_V, 1);
    gemm_k<<<dim3(8, 2), 256, 0, stream>>>(Q + (long long)S_V * 2048, exp_o_w, OUTE,
        embeds_exp, MOD1, 2048, 256, 1024, 2048, S_E, QBS,
        (long long)S_E * W_E, (long long)S_E * W_E, 1 | 2);

    // 8) second norms
    rms_scale_k<<<BATCH * S_V, 256, 0, stream>>>(OUTV, vlm_ln2_w, W0, W_V);
    rms_mod_k<<<BATCH * S_E, 256, 0, stream>>>(OUTE, MOD2, W1, W_E, S_E);

    // 9) VLM MLP, chunked by 384 rows
    for (int ci = 0; ci < 8; ci++) {
        const float* Ac = W0 + (long long)ci * 384 * W_V;
        gemm_k<<<dim3(128, 3), 256, 0, stream>>>(Ac, vlm_gate_w, AG, nullptr, nullptr, 0,
            384, MLP_V, W_V, 384, 0, 0, 0, 0);
        gemm_k<<<dim3(128, 3), 256, 0, stream>>>(Ac, vlm_up_w, AU, nullptr, nullptr, 0,
            384, MLP_V, W_V, 384, 0, 0, 0, 0);
        gelu_mul_k<<<8192, 256, 0, stream>>>(AG, AU, (long long)384 * MLP_V);
        gemm_k<<<dim3(16, 3), 256, 0, stream>>>(AG, vlm_down_w,
            OUTV + (long long)ci * 384 * W_V, nullptr, nullptr, 0,
            384, W_V, MLP_V, 384, 0, 0, 0, 4);
    }

    // 10) expert MLP (gated accumulate)
    gemm_k<<<dim3(32, 2), 256, 0, stream>>>(W1, exp_gate_w, AG, nullptr, nullptr, 0,
        256, MLP_E, W_E, 256, 0, 0, 0, 0);
    gemm_k<<<dim3(32, 2), 256, 0, stream>>>(W1, exp_up_w, AU, nullptr, nullptr, 0,
        256, MLP_E, W_E, 256, 0, 0, 0, 0);
    gelu_mul_k<<<4096, 256, 0, stream>>>(AG, AU, (long long)256 * MLP_E);
    gemm_k<<<dim3(8, 2), 256, 0, stream>>>(AG, exp_down_w, OUTE, nullptr, MOD2, 2048,
        256, W_E, MLP_E, S_E, (long long)S_E * MLP_E, (long long)S_E * W_E, 0, 4 | 2);
}

// Round 2
// 4791.312 us; speedup vs baseline: 7.6141x; 7.6141x over previous
//
#include <hip/hip_runtime.h>
#include <math.h>

// ---------------------------------------------------------------------------
// Problem constants
// ---------------------------------------------------------------------------
#define BATCH 4
#define S_V 768
#define S_E 64
#define SEQ 832
#define W_V 2048
#define W_E 1024
#define NH 8
#define DH 256
#define MLP_V 16384
#define MLP_E 4096
#define EPS 1e-6f
#define ATT_SCALE 0.0625f

typedef __attribute__((ext_vector_type(8))) __bf16 bf16x8;
typedef __attribute__((ext_vector_type(4))) float f32x4;

__device__ __forceinline__ short f2bf(float f) {
    union { float f; unsigned u; } v; v.f = f;
    unsigned r = v.u + 0x7FFFu + ((v.u >> 16) & 1u);
    return (short)(r >> 16);
}
__device__ __forceinline__ float bf2f(short s) {
    union { unsigned u; float f; } v;
    v.u = ((unsigned)(unsigned short)s) << 16;
    return v.f;
}

// global -> LDS direct DMA, 16B per lane (m97 pattern).
// LDS dest must be wave-uniform base + lane*16 (our staging layout is linear in tid).
#define G2L(gp, lp)                                                          \
    __builtin_amdgcn_global_load_lds(                                        \
        (const __attribute__((address_space(1))) unsigned int*)              \
            (unsigned long long)(const void*)(gp),                           \
        (__attribute__((address_space(3))) unsigned int*)                    \
            (unsigned int)(unsigned long long)(const void*)(lp),             \
        16, 0, 0)

// ---------------------------------------------------------------------------
// bf16 MFMA GEMM, m97 structure: 128x128 tile, BK=32, 4 waves, 16x16x32 MFMA.
//   A: bf16, row m at A + (m/rpb)*a_bs + (m%rpb)*K   (set a_bs=rpb*K if contiguous)
//   Bt: bf16 [N][K] row-major (pre-transposed weight)
//   C/Cb: row m at base + (m/rpb)*c_bs + (m%rpb)*N
//   flags: 1=+res, 2=*gate[b*3072+gate_off+n], 4=+=C (f32 accum), 8=write bf16 to Cb
// Grid: (N/128, M/128), block 256.
// ---------------------------------------------------------------------------
__global__ __launch_bounds__(256) void bgemm_k(
    const short* __restrict__ A, const short* __restrict__ Bt,
    float* __restrict__ C, short* __restrict__ Cb,
    const float* __restrict__ res, const float* __restrict__ gate, int gate_off,
    int N, int K, int rpb,
    long long a_bs, long long c_bs, long long r_bs, int flags)
{
    __shared__ short Asd[4096];   // [128][32] bf16 row-major, 64B rows
    __shared__ short Bsd[4096];   // [128][32]

    const int t  = threadIdx.x;
    const int bm = blockIdx.y * 128;
    const int bn = blockIdx.x * 128;

    // staging sources: each thread stages 2x16B of A-tile and 2x16B of B-tile
    const short* gA[2];
    const short* gB[2];
    int lof[2];
#pragma unroll
    for (int l = 0; l < 2; l++) {
        int off = l * 4096 + t * 16;       // byte offset within 8KB tile
        int row = off >> 6;                // 64B per LDS row
        int kel = (off & 63) >> 1;         // bf16 element offset within k-tile
        lof[l] = off;
        int m = bm + row;
        gA[l] = A + (long long)(m / rpb) * a_bs + (long long)(m % rpb) * K + kel;
        gB[l] = Bt + (long long)(bn + row) * K + kel;
    }

    const int lane = t & 63;
    const int w    = t >> 6;
    const int wm   = (w >> 1) * 64;
    const int wn   = (w & 1) * 64;
    const int lr   = lane & 15;
    const int quad = lane >> 4;

    f32x4 acc[4][4];
#pragma unroll
    for (int i = 0; i < 4; i++)
#pragma unroll
        for (int j = 0; j < 4; j++) acc[i][j] = (f32x4){0.f, 0.f, 0.f, 0.f};

    for (int k0 = 0; k0 < K; k0 += 32) {
        __syncthreads();               // previous tile consumed
#pragma unroll
        for (int l = 0; l < 2; l++) {
            G2L(gA[l] + k0, (char*)Asd + lof[l]);
            G2L(gB[l] + k0, (char*)Bsd + lof[l]);
        }
        __syncthreads();               // drain vmcnt, staged data visible

        bf16x8 af[4], bfr[4];
#pragma unroll
        for (int i = 0; i < 4; i++)
            af[i] = *(const bf16x8*)&Asd[(wm + i * 16 + lr) * 32 + quad * 8];
#pragma unroll
        for (int j = 0; j < 4; j++)
            bfr[j] = *(const bf16x8*)&Bsd[(wn + j * 16 + lr) * 32 + quad * 8];
#pragma unroll
        for (int i = 0; i < 4; i++)
#pragma unroll
            for (int j = 0; j < 4; j++)
                acc[i][j] = __builtin_amdgcn_mfma_f32_16x16x32_bf16(
                    af[i], bfr[j], acc[i][j], 0, 0, 0);
    }

    // epilogue: D row = quad*4+reg, col = lane&15 (m89-verified layout)
#pragma unroll
    for (int i = 0; i < 4; i++) {
#pragma unroll
        for (int r = 0; r < 4; r++) {
            int m = bm + wm + i * 16 + quad * 4 + r;
            long long bb = m / rpb;
            long long ss = m % rpb;
            long long rowb = bb * c_bs + ss * (long long)N;
            const float* rp = (flags & 1) ? res + bb * r_bs + ss * (long long)N : nullptr;
            const float* gp = (flags & 2) ? gate + bb * 3072 + gate_off : nullptr;
#pragma unroll
            for (int j = 0; j < 4; j++) {
                int n = bn + wn + j * 16 + lr;
                float v = acc[i][j][r];
                if (flags & 2) v *= gp[n];
                if (flags & 4) v += C[rowb + n];
                if (flags & 1) v += rp[n];
                if (flags & 8) Cb[rowb + n] = f2bf(v);
                else           C[rowb + n] = v;
            }
        }
    }
}

// ---------------------------------------------------------------------------
// Transpose + f32->bf16: W[K][N] f32  ->  Wt[N][K] bf16.  Grid (N/64, K/64).
// ---------------------------------------------------------------------------
__global__ __launch_bounds__(256) void tcvt_k(
    const float* __restrict__ W, short* __restrict__ Wt, int K, int N)
{
    __shared__ float tile[64][65];
    const int bx = blockIdx.x;   // N / 64
    const int by = blockIdx.y;   // K / 64
    const int t = threadIdx.x;
#pragma unroll
    for (int p = 0; p < 4; p++) {
        int idx = p * 256 + t;            // 0..1023
        int r = idx >> 4;                 // k-row 0..63
        int c4 = (idx & 15) << 2;         // 0..60
        float4 v = *(const float4*)&W[(long long)(by * 64 + r) * N + bx * 64 + c4];
        tile[r][c4] = v.x; tile[r][c4 + 1] = v.y;
        tile[r][c4 + 2] = v.z; tile[r][c4 + 3] = v.w;
    }
    __syncthreads();
#pragma unroll
    for (int p = 0; p < 8; p++) {
        int idx = p * 256 + t;            // 0..2047
        int n  = idx >> 5;                // 0..63
        int kp = idx & 31;                // k-pair 0..31
        unsigned lo = (unsigned)(unsigned short)f2bf(tile[kp * 2][n]);
        unsigned hi = (unsigned)(unsigned short)f2bf(tile[kp * 2 + 1][n]);
        *(unsigned*)&Wt[(long long)(bx * 64 + n) * K + by * 64 + kp * 2] =
            lo | (hi << 16);
    }
}

// ---------------------------------------------------------------------------
// RMSNorm * (1+w) -> bf16
// ---------------------------------------------------------------------------
__global__ __launch_bounds__(256) void rms_scale_bf(
    const float* __restrict__ x, const float* __restrict__ w,
    short* __restrict__ out, int C)
{
    const int row = blockIdx.x;
    const int t = threadIdx.x;
    const float* xp = x + (long long)row * C;
    short* op = out + (long long)row * C;
    float ss = 0.f;
    for (int i = t; i < C; i += 256) { float v = xp[i]; ss += v * v; }
    __shared__ float sred[256];
    sred[t] = ss;
    __syncthreads();
    for (int off = 128; off > 0; off >>= 1) {
        if (t < off) sred[t] += sred[t + off];
        __syncthreads();
    }
    float scale = rsqrtf(sred[0] / (float)C + EPS);
    for (int i = t; i < C; i += 256) op[i] = f2bf(xp[i] * scale * (1.f + w[i]));
}

// adaLN RMSNorm -> bf16 : rms(x)*(1+mod[b,i]) + mod[b,C+i]
__global__ __launch_bounds__(256) void rms_mod_bf(
    const float* __restrict__ x, const float* __restrict__ mod,
    short* __restrict__ out, int C, int rows_per_b)
{
    const int row = blockIdx.x;
    const int t = threadIdx.x;
    const int b = row / rows_per_b;
    const float* xp = x + (long long)row * C;
    const float* mp = mod + (long long)b * 3072;
    short* op = out + (long long)row * C;
    float ss = 0.f;
    for (int i = t; i < C; i += 256) { float v = xp[i]; ss += v * v; }
    __shared__ float sred[256];
    sred[t] = ss;
    __syncthreads();
    for (int off = 128; off > 0; off >>= 1) {
        if (t < off) sred[t] += sred[t + off];
        __syncthreads();
    }
    float scale = rsqrtf(sred[0] / (float)C + EPS);
    for (int i = t; i < C; i += 256)
        op[i] = f2bf(xp[i] * scale * (1.f + mp[i]) + mp[C + i]);
}

// ---------------------------------------------------------------------------
// Modulation: mod[b,n] = cond[b,:] @ dw[:,n] + db[n]   (K=1024, N=3072)
// ---------------------------------------------------------------------------
__global__ __launch_bounds__(256) void modln_k(
    const float* __restrict__ cond, const float* __restrict__ dw,
    const float* __restrict__ db, float* __restrict__ out)
{
    const int b = blockIdx.y;
    const int n = blockIdx.x * 256 + threadIdx.x;
    __shared__ float cs[1024];
    for (int i = threadIdx.x; i < 1024; i += 256) cs[i] = cond[b * 1024 + i];
    __syncthreads();
    float acc = db[n];
    for (int k = 0; k < 1024; k++) acc += cs[k] * dw[(long long)k * 3072 + n];
    out[b * 3072 + n] = acc;
}

// ---------------------------------------------------------------------------
// RoPE (f32, in place). x[B,SEQ,heads,DH]; grid (B*SEQ, heads), block 128.
// ---------------------------------------------------------------------------
__global__ __launch_bounds__(128) void rope_k(
    float* __restrict__ x, const int* __restrict__ pos_ids, int heads)
{
    const int bs = blockIdx.x;
    const int h = blockIdx.y;
    const int d = threadIdx.x;
    const float p = (float)pos_ids[bs];
    const float inv = powf(10000.f, -(float)d / 128.f);
    const float fr = p * inv;
    const float c = cosf(fr), sn = sinf(fr);
    float* xp = x + ((long long)bs * heads + h) * DH;
    float x1 = xp[d];
    float x2 = xp[d + 128];
    xp[d]       = x1 * c - x2 * sn;
    xp[d + 128] = x2 * c + x1 * sn;
}

// ---------------------------------------------------------------------------
// Attention (f32 in, bf16 out). q[B,SEQ,NH*DH], k/v[B,SEQ,DH] (HKV=1).
// ---------------------------------------------------------------------------
__global__ __launch_bounds__(256) void attn_k(
    const float* __restrict__ q, const float* __restrict__ k,
    const float* __restrict__ v, short* __restrict__ out)
{
    const int r0 = blockIdx.x * 8;
    const int h = blockIdx.y;
    const int b = blockIdx.z;
    const int t = threadIdx.x;

    __shared__ float qs[8][DH];
    __shared__ float ps[8][SEQ];
    __shared__ float sred[256];
    __shared__ float srinv[8];

#pragma unroll
    for (int r8 = 0; r8 < 8; r8++)
        qs[r8][t] = q[((long long)(b * SEQ + r0 + r8) * NH + h) * DH + t];
    __syncthreads();

    for (int p = t; p < 8 * SEQ; p += 256) {
        int r8 = p / SEQ;
        int kk = p % SEQ;
        int r = r0 + r8;
        bool ok = (kk < S_V) || (r >= S_V && kk <= r);
        if (ok) {
            const float4* kp = (const float4*)(k + (long long)(b * SEQ + kk) * DH);
            const float4* qp = (const float4*)qs[r8];
            float acc = 0.f;
#pragma unroll 4
            for (int d4 = 0; d4 < DH / 4; d4++) {
                float4 kv = kp[d4];
                float4 qv = qp[d4];
                acc += qv.x * kv.x + qv.y * kv.y + qv.z * kv.z + qv.w * kv.w;
            }
            ps[r8][kk] = acc * ATT_SCALE;
        } else {
            ps[r8][kk] = -1e30f;
        }
    }
    __syncthreads();

    for (int r8 = 0; r8 < 8; r8++) {
        float lm = -1e30f;
        for (int kk = t; kk < SEQ; kk += 256) lm = fmaxf(lm, ps[r8][kk]);
        sred[t] = lm;
        __syncthreads();
        for (int off = 128; off > 0; off >>= 1) {
            if (t < off) sred[t] = fmaxf(sred[t], sred[t + off]);
            __syncthreads();
        }
        float m = sred[0];
        __syncthreads();
        float lsum = 0.f;
        for (int kk = t; kk < SEQ; kk += 256) {
            float e = expf(ps[r8][kk] - m);
            ps[r8][kk] = e;
            lsum += e;
        }
        sred[t] = lsum;
        __syncthreads();
        for (int off = 128; off > 0; off >>= 1) {
            if (t < off) sred[t] += sred[t + off];
            __syncthreads();
        }
        if (t == 0) srinv[r8] = 1.f / sred[0];
        __syncthreads();
    }

    float acc[8];
#pragma unroll
    for (int r8 = 0; r8 < 8; r8++) acc[r8] = 0.f;
    for (int kk = 0; kk < SEQ; kk++) {
        float vv = v[(long long)(b * SEQ + kk) * DH + t];
#pragma unroll
        for (int r8 = 0; r8 < 8; r8++) acc[r8] += ps[r8][kk] * vv;
    }
#pragma unroll
    for (int r8 = 0; r8 < 8; r8++)
        out[((long long)(b * SEQ + r0 + r8) * NH + h) * DH + t] =
            f2bf(acc[r8] * srinv[r8]);
}

// ---------------------------------------------------------------------------
// g = gelu_tanh(g) * u  (bf16, 4 elements per thread)
// ---------------------------------------------------------------------------
__global__ __launch_bounds__(256) void gelu_mul_bf(
    short* __restrict__ g, const short* __restrict__ u, long long n4)
{
    long long i = (long long)blockIdx.x * 256 + threadIdx.x;
    if (i >= n4) return;
    uint2 gv = ((const uint2*)g)[i];
    uint2 uv = ((const uint2*)u)[i];
    unsigned w[2] = {gv.x, gv.y};
    unsigned ww[2] = {uv.x, uv.y};
    unsigned o[2];
#pragma unroll
    for (int p = 0; p < 2; p++) {
        unsigned res = 0;
#pragma unroll
        for (int h = 0; h < 2; h++) {
            float x = bf2f((short)((w[p] >> (16 * h)) & 0xFFFF));
            float uu = bf2f((short)((ww[p] >> (16 * h)) & 0xFFFF));
            float th = tanhf(0.7978845608028654f * (x + 0.044715f * x * x * x));
            float r = 0.5f * x * (1.f + th) * uu;
            res |= ((unsigned)(unsigned short)f2bf(r)) << (16 * h);
        }
        o[p] = res;
    }
    ((uint2*)g)[i] = make_uint2(o[0], o[1]);
}

// ---------------------------------------------------------------------------
// kernel_launch
// ---------------------------------------------------------------------------
extern "C" void kernel_launch(void* const* d_in, const int* in_sizes, int n_in,
                              void* d_out, int out_size, void* d_ws, size_t ws_size,
                              hipStream_t stream)
{
    const float* embeds_vlm = (const float*)d_in[0];
    const float* embeds_exp = (const float*)d_in[1];
    const float* cond       = (const float*)d_in[2];
    const float* vlm_ln1_w  = (const float*)d_in[3];
    const float* vlm_ln2_w  = (const float*)d_in[4];
    const float* vlm_q_w    = (const float*)d_in[5];
    const float* vlm_k_w    = (const float*)d_in[6];
    const float* vlm_v_w    = (const float*)d_in[7];
    const float* vlm_o_w    = (const float*)d_in[8];
    const float* vlm_gate_w = (const float*)d_in[9];
    const float* vlm_up_w   = (const float*)d_in[10];
    const float* vlm_down_w = (const float*)d_in[11];
    const float* exp_ln1_dw = (const float*)d_in[12];
    const float* exp_ln1_db = (const float*)d_in[13];
    const float* exp_ln2_dw = (const float*)d_in[14];
    const float* exp_ln2_db = (const float*)d_in[15];
    const float* exp_q_w    = (const float*)d_in[16];
    const float* exp_k_w    = (const float*)d_in[17];
    const float* exp_v_w    = (const float*)d_in[18];
    const float* exp_o_w    = (const float*)d_in[19];
    const float* exp_gate_w = (const float*)d_in[20];
    const float* exp_up_w   = (const float*)d_in[21];
    const float* exp_down_w = (const float*)d_in[22];
    const int*   position_ids = (const int*)d_in[23];

    float* OUTV = (float*)d_out;
    float* OUTE = OUTV + (long long)BATCH * S_V * W_V;

    // ---- workspace carve-up ----
    char* p = (char*)d_ws;
    auto alloc = [&](size_t bytes) {
        char* r = p; p += (bytes + 255) & ~(size_t)255; return r;
    };
    short* WT_VQ = (short*)alloc(2048ULL * 2048 * 2);
    short* WT_VK = (short*)alloc(256ULL  * 2048 * 2);
    short* WT_VV = (short*)alloc(256ULL  * 2048 * 2);
    short* WT_VO = (short*)alloc(2048ULL * 2048 * 2);
    short* WT_VG = (short*)alloc(16384ULL * 2048 * 2);
    short* WT_VU = (short*)alloc(16384ULL * 2048 * 2);
    short* WT_VD = (short*)alloc(2048ULL * 16384 * 2);
    short* WT_EQ = (short*)alloc(2048ULL * 1024 * 2);
    short* WT_EK = (short*)alloc(256ULL  * 1024 * 2);
    short* WT_EV = (short*)alloc(256ULL  * 1024 * 2);
    short* WT_EO = (short*)alloc(1024ULL * 2048 * 2);
    short* WT_EG = (short*)alloc(4096ULL * 1024 * 2);
    short* WT_EU = (short*)alloc(4096ULL * 1024 * 2);
    short* WT_ED = (short*)alloc(1024ULL * 4096 * 2);
    short* W0h = (short*)alloc(3072ULL * 2048 * 2);
    short* W1h = (short*)alloc(256ULL * 1024 * 2);
    float* MOD1 = (float*)alloc(4ULL * 3072 * 4);
    float* MOD2 = (float*)alloc(4ULL * 3072 * 4);
    float* Q  = (float*)alloc(4ULL * 832 * 2048 * 4);
    float* Kb = (float*)alloc(4ULL * 832 * 256 * 4);
    float* Vb = (float*)alloc(4ULL * 832 * 256 * 4);
    short* QB = (short*)alloc(4ULL * 832 * 2048 * 2);
    size_t fixed = (size_t)(p - (char*)d_ws);
    // MLP activation chunk: full 3072 rows if ws allows, else 768-row chunks
    int CR = 3072;
    if (fixed + 2ULL * 3072 * 16384 * 2 + 1024 > ws_size) CR = 768;
    short* G = (short*)alloc((size_t)CR * MLP_V * 2);
    short* U = (short*)alloc((size_t)CR * MLP_V * 2);

    const long long QBS = (long long)SEQ * 2048;   // 832*2048
    const long long KBS = (long long)SEQ * 256;

    // ---- 1) weight transpose+convert (W[K][N] f32 -> Wt[N][K] bf16) ----
    tcvt_k<<<dim3(2048/64, 2048/64), 256, 0, stream>>>(vlm_q_w, WT_VQ, 2048, 2048);
    tcvt_k<<<dim3(256/64,  2048/64), 256, 0, stream>>>(vlm_k_w, WT_VK, 2048, 256);
    tcvt_k<<<dim3(256/64,  2048/64), 256, 0, stream>>>(vlm_v_w, WT_VV, 2048, 256);
    tcvt_k<<<dim3(2048/64, 2048/64), 256, 0, stream>>>(vlm_o_w, WT_VO, 2048, 2048);
    tcvt_k<<<dim3(16384/64,2048/64), 256, 0, stream>>>(vlm_gate_w, WT_VG, 2048, 16384);
    tcvt_k<<<dim3(16384/64,2048/64), 256, 0, stream>>>(vlm_up_w,   WT_VU, 2048, 16384);
    tcvt_k<<<dim3(2048/64,16384/64), 256, 0, stream>>>(vlm_down_w, WT_VD, 16384, 2048);
    tcvt_k<<<dim3(2048/64, 1024/64), 256, 0, stream>>>(exp_q_w, WT_EQ, 1024, 2048);
    tcvt_k<<<dim3(256/64,  1024/64), 256, 0, stream>>>(exp_k_w, WT_EK, 1024, 256);
    tcvt_k<<<dim3(256/64,  1024/64), 256, 0, stream>>>(exp_v_w, WT_EV, 1024, 256);
    tcvt_k<<<dim3(1024/64, 2048/64), 256, 0, stream>>>(exp_o_w, WT_EO, 2048, 1024);
    tcvt_k<<<dim3(4096/64, 1024/64), 256, 0, stream>>>(exp_gate_w, WT_EG, 1024, 4096);
    tcvt_k<<<dim3(4096/64, 1024/64), 256, 0, stream>>>(exp_up_w,   WT_EU, 1024, 4096);
    tcvt_k<<<dim3(1024/64, 4096/64), 256, 0, stream>>>(exp_down_w, WT_ED, 4096, 1024);

    // ---- 2) norms + modulation ----
    rms_scale_bf<<<BATCH * S_V, 256, 0, stream>>>(embeds_vlm, vlm_ln1_w, W0h, W_V);
    modln_k<<<dim3(12, BATCH), 256, 0, stream>>>(cond, exp_ln1_dw, exp_ln1_db, MOD1);
    modln_k<<<dim3(12, BATCH), 256, 0, stream>>>(cond, exp_ln2_dw, exp_ln2_db, MOD2);
    rms_mod_bf<<<BATCH * S_E, 256, 0, stream>>>(embeds_exp, MOD1, W1h, W_E, S_E);

    // ---- 3) q/k/v projections ----
    bgemm_k<<<dim3(16, 24), 256, 0, stream>>>(W0h, WT_VQ, Q, nullptr, nullptr, nullptr, 0,
        2048, 2048, S_V, (long long)S_V * 2048, QBS, 0, 0);
    bgemm_k<<<dim3(2, 24), 256, 0, stream>>>(W0h, WT_VK, Kb, nullptr, nullptr, nullptr, 0,
        256, 2048, S_V, (long long)S_V * 2048, KBS, 0, 0);
    bgemm_k<<<dim3(2, 24), 256, 0, stream>>>(W0h, WT_VV, Vb, nullptr, nullptr, nullptr, 0,
        256, 2048, S_V, (long long)S_V * 2048, KBS, 0, 0);
    bgemm_k<<<dim3(16, 2), 256, 0, stream>>>(W1h, WT_EQ, Q + (long long)S_V * 2048,
        nullptr, nullptr, nullptr, 0, 2048, 1024, S_E, (long long)S_E * 1024, QBS, 0, 0);
    bgemm_k<<<dim3(2, 2), 256, 0, stream>>>(W1h, WT_EK, Kb + (long long)S_V * 256,
        nullptr, nullptr, nullptr, 0, 256, 1024, S_E, (long long)S_E * 1024, KBS, 0, 0);
    bgemm_k<<<dim3(2, 2), 256, 0, stream>>>(W1h, WT_EV, Vb + (long long)S_V * 256,
        nullptr, nullptr, nullptr, 0, 256, 1024, S_E, (long long)S_E * 1024, KBS, 0, 0);

    // ---- 4) RoPE + attention ----
    rope_k<<<dim3(BATCH * SEQ, NH), 128, 0, stream>>>(Q, position_ids, NH);
    rope_k<<<dim3(BATCH * SEQ, 1), 128, 0, stream>>>(Kb, position_ids, 1);
    attn_k<<<dim3(SEQ / 8, NH, BATCH), 256, 0, stream>>>(Q, Kb, Vb, QB);

    // ---- 5) o-projections (+residual, expert gated) ----
    bgemm_k<<<dim3(16, 24), 256, 0, stream>>>(QB, WT_VO, OUTV, nullptr,
        embeds_vlm, nullptr, 0, 2048, 2048, S_V, QBS,
        (long long)S_V * 2048, (long long)S_V * 2048, 1);
    bgemm_k<<<dim3(8, 2), 256, 0, stream>>>(QB + (long long)S_V * 2048, WT_EO, OUTE,
        nullptr, embeds_exp, MOD1, 2048, 1024, 2048, S_E, QBS,
        (long long)S_E * 1024, (long long)S_E * 1024, 1 | 2);

    // ---- 6) second norms ----
    rms_scale_bf<<<BATCH * S_V, 256, 0, stream>>>(OUTV, vlm_ln2_w, W0h, W_V);
    rms_mod_bf<<<BATCH * S_E, 256, 0, stream>>>(OUTE, MOD2, W1h, W_E, S_E);

    // ---- 7) VLM MLP ----
    for (int c0 = 0; c0 < 3072; c0 += CR) {
        const short* Ac = W0h + (long long)c0 * 2048;
        long long g4 = (long long)CR * MLP_V / 4;
        bgemm_k<<<dim3(MLP_V / 128, CR / 128), 256, 0, stream>>>(Ac, WT_VG,
            nullptr, G, nullptr, nullptr, 0, MLP_V, 2048, CR,
            (long long)CR * 2048, (long long)CR * MLP_V, 0, 8);
        bgemm_k<<<dim3(MLP_V / 128, CR / 128), 256, 0, stream>>>(Ac, WT_VU,
            nullptr, U, nullptr, nullptr, 0, MLP_V, 2048, CR,
            (long long)CR * 2048, (long long)CR * MLP_V, 0, 8);
        gelu_mul_bf<<<(int)((g4 + 255) / 256), 256, 0, stream>>>(G, U, g4);
        bgemm_k<<<dim3(2048 / 128, CR / 128), 256, 0, stream>>>(G, WT_VD,
            OUTV + (long long)c0 * 2048, nullptr, nullptr, nullptr, 0,
            2048, MLP_V, CR, (long long)CR * MLP_V, (long long)CR * 2048, 0, 4);
    }

    // ---- 8) expert MLP (gated accumulate) ----
    bgemm_k<<<dim3(MLP_E / 128, 2), 256, 0, stream>>>(W1h, WT_EG,
        nullptr, G, nullptr, nullptr, 0, MLP_E, 1024, S_E,
        (long long)S_E * 1024, (long long)S_E * MLP_E, 0, 8);
    bgemm_k<<<dim3(MLP_E / 128, 2), 256, 0, stream>>>(W1h, WT_EU,
        nullptr, U, nullptr, nullptr, 0, MLP_E, 1024, S_E,
        (long long)S_E * 1024, (long long)S_E * MLP_E, 0, 8);
    long long e4 = (long long)256 * MLP_E / 4;
    gelu_mul_bf<<<(int)((e4 + 255) / 256), 256, 0, stream>>>(G, U, e4);
    bgemm_k<<<dim3(1024 / 128, 2), 256, 0, stream>>>(G, WT_ED, OUTE, nullptr,
        nullptr, MOD2, 2048, 1024, MLP_E, S_E,
        (long long)S_E * MLP_E, (long long)S_E * 1024, 0, 4 | 2);
}